// Round 5
// baseline (1259.989 us; speedup 1.0000x reference)
//
#include <hip/hip_runtime.h>

// Problem constants (from reference)
#define NU 200000
#define NI 100000
#define DIM 64
#define NE 3200000
#define NT (NU + NI)                     // concatenated destination count
#define CHUNK 2048                       // elements per scan block (256 thr x 8)
#define NB ((NT + CHUNK - 1) / CHUNK)    // 147 scan blocks

static_assert(NB <= 256, "scan2 assumes block sums fit one 256-thread block");
static_assert((NE & 3) == 0, "int4 edge vectorization assumes NE % 4 == 0");

// Established (R0-R8):
//  - ALL float inputs f32; edges int32, dict order. Output F32, users then items.
//  - Edge-order detector (flag[3]) validated in R7.
// R11 (CSR, 1088 us): scatter 360 us @ WRITE 595 MB (two 4 B stores/slot, 2
//  dirty sectors), 1.75 TB/s; rest 728 us.
// R12 (1215 us): int2 packing DID cut WRITE to 396 MB (one ~32 B sector/slot)
//  but halving scatter threads + serial 8-deep atomic chains dropped store
//  throughput to 0.74 TB/s -> scatter 575 us. Rest improved to 640 us (spmm
//  4-way MLP kept). Lesson: the scatter is latency-limited; parallelism is
//  the lever, bytes are secondary.
// R13: scatter = R11 parallelism (1 edge/thread, 3200 blocks, grid-stride)
//  + R12 packed int2 payload. Hist/int4 + spmm/float4-groups kept from R12.

__device__ __forceinline__ int iclamp(int x, int lo, int hi) {
    return x < lo ? lo : (x > hi ? hi : x);
}

__global__ void zero_i32_kernel(int* __restrict__ p, long long n) {
    long long i = (long long)blockIdx.x * blockDim.x + threadIdx.x;
    long long stride = (long long)gridDim.x * blockDim.x;
    for (; i < n; i += stride) p[i] = 0;
}

__global__ void zero_f32_kernel(float* __restrict__ p, long long n) {
    long long i = (long long)blockIdx.x * blockDim.x + threadIdx.x;
    long long stride = (long long)gridDim.x * blockDim.x;
    for (; i < n; i += stride) p[i] = 0.0f;
}

// flag: [3]=edge_swap  [10]=maxA [11]=maxB  (validated in R7)
__global__ void edge_detect_kernel(const int* __restrict__ a, const int* __restrict__ b,
                                   int n, int* __restrict__ flag) {
    int i = blockIdx.x * blockDim.x + threadIdx.x;
    int stride = gridDim.x * blockDim.x;
    int ma = 0, mb = 0;
    for (; i < n; i += stride) {
        ma = max(ma, a[i]);
        mb = max(mb, b[i]);
    }
    #pragma unroll
    for (int d = 32; d > 0; d >>= 1) {
        ma = max(ma, __shfl_down(ma, d, 64));
        mb = max(mb, __shfl_down(mb, d, 64));
    }
    if ((threadIdx.x & 63) == 0) {
        atomicMax(&flag[10], ma);
        atomicMax(&flag[11], mb);
    }
}
__global__ void finalize_kernel(int* __restrict__ flag) {
    if (threadIdx.x == 0 && blockIdx.x == 0) {
        int ma = flag[10], mb = flag[11];
        flag[3] = (mb >= NI && ma < NI) ? 1 : 0;
    }
}

// ---------------------------------------------------------------------------
// CSR build: histogram over concatenated destinations (users [0,NU), items
// [NU,NT)). int4-vectorized edge reads; int atomics are cheap packets.
// ---------------------------------------------------------------------------
__global__ __launch_bounds__(256) void hist_kernel(
        const int* __restrict__ a, const int* __restrict__ b,
        const int* __restrict__ flag, int* __restrict__ cnt) {
    int sw = flag[3];
    const int4* eu4 = (const int4*)(sw ? b : a);
    const int4* ei4 = (const int4*)(sw ? a : b);
    int e4 = blockIdx.x * blockDim.x + threadIdx.x;
    int stride = gridDim.x * blockDim.x;
    for (; e4 < NE / 4; e4 += stride) {
        int4 uu = eu4[e4];
        int4 ii = ei4[e4];
        atomicAdd(&cnt[iclamp(uu.x, 0, NU - 1)], 1);
        atomicAdd(&cnt[iclamp(uu.y, 0, NU - 1)], 1);
        atomicAdd(&cnt[iclamp(uu.z, 0, NU - 1)], 1);
        atomicAdd(&cnt[iclamp(uu.w, 0, NU - 1)], 1);
        atomicAdd(&cnt[NU + iclamp(ii.x, 0, NI - 1)], 1);
        atomicAdd(&cnt[NU + iclamp(ii.y, 0, NI - 1)], 1);
        atomicAdd(&cnt[NU + iclamp(ii.z, 0, NI - 1)], 1);
        atomicAdd(&cnt[NU + iclamp(ii.w, 0, NI - 1)], 1);
    }
}

// Two-level exclusive scan over cnt[0..NT). User region sums to exactly NE,
// so rowptr[u] in [0,NE) and rowptr[NU+i] in [NE,2NE): one combined slot space.
__global__ __launch_bounds__(256) void scan1_kernel(const int* __restrict__ cnt,
                                                    int* __restrict__ bsum) {
    int b = blockIdx.x, t = threadIdx.x;
    int base = b * CHUNK;
    int sum = 0;
    #pragma unroll
    for (int k = 0; k < 8; ++k) {
        int idx = base + k * 256 + t;
        if (idx < NT) sum += cnt[idx];
    }
    #pragma unroll
    for (int d = 32; d > 0; d >>= 1) sum += __shfl_down(sum, d, 64);
    __shared__ int wsum[4];
    if ((t & 63) == 0) wsum[t >> 6] = sum;
    __syncthreads();
    if (t == 0) bsum[b] = wsum[0] + wsum[1] + wsum[2] + wsum[3];
}

__global__ __launch_bounds__(256) void scan2_kernel(int* __restrict__ bsum) {
    __shared__ int sh[256];
    int t = threadIdx.x;
    sh[t] = (t < NB) ? bsum[t] : 0;
    __syncthreads();
    for (int off = 1; off < 256; off <<= 1) {
        int v = (t >= off) ? sh[t - off] : 0;
        __syncthreads();
        sh[t] += v;
        __syncthreads();
    }
    if (t < NB) bsum[t] = (t == 0) ? 0 : sh[t - 1];   // exclusive
}

__global__ __launch_bounds__(256) void scan3_kernel(const int* __restrict__ cnt,
                                                    const int* __restrict__ bsum,
                                                    int* __restrict__ rowptr,
                                                    int* __restrict__ cursor) {
    int b = blockIdx.x, t = threadIdx.x;
    int base = b * CHUNK + t * 8;     // 8 contiguous elements per thread
    int v[8];
    int s = 0;
    #pragma unroll
    for (int k = 0; k < 8; ++k) {
        int idx = base + k;
        v[k] = (idx < NT) ? cnt[idx] : 0;
        s += v[k];
    }
    __shared__ int sh[256];
    sh[t] = s;
    __syncthreads();
    for (int off = 1; off < 256; off <<= 1) {
        int x = (t >= off) ? sh[t - off] : 0;
        __syncthreads();
        sh[t] += x;
        __syncthreads();
    }
    int run = (t == 0 ? 0 : sh[t - 1]) + bsum[b];
    #pragma unroll
    for (int k = 0; k < 8; ++k) {
        int idx = base + k;
        if (idx < NT) {
            rowptr[idx] = run;
            cursor[idx] = run;
            run += v[k];
        }
        if (idx == NT - 1) rowptr[NT] = run;   // == 2*NE
    }
}

// Scatter edges into sorted slots as packed (col, val_bits) int2 — one 8 B
// store per slot. One edge per thread, grid-stride (R11 parallelism: this
// phase is latency-limited; independent chains in flight are the lever).
// Every slot in pairS[0..2*NE) is written exactly once; no pre-zero needed.
__global__ __launch_bounds__(256) void scatter_kernel(
        const int* __restrict__ a, const int* __restrict__ b,
        const int* __restrict__ flag, const float* __restrict__ ev,
        int* __restrict__ cursor, int2* __restrict__ pairS) {
    int sw = flag[3];
    const int* eu = sw ? b : a;
    const int* ei = sw ? a : b;
    int e = blockIdx.x * blockDim.x + threadIdx.x;
    int stride = gridDim.x * blockDim.x;
    for (; e < NE; e += stride) {
        int u = iclamp(eu[e], 0, NU - 1);
        int i = iclamp(ei[e], 0, NI - 1);
        int vb = __float_as_int(ev[e]);
        int p0 = atomicAdd(&cursor[u], 1);       // user slot: stores item idx
        pairS[p0] = make_int2(i, vb);
        int p1 = atomicAdd(&cursor[NU + i], 1);  // item slot: stores user idx
        pairS[p1] = make_int2(u, vb);
    }
}

// ---------------------------------------------------------------------------
// Gather SpMM: one wave per output row. 4 edges in flight per iteration:
// 16-lane groups (g = lane>>4), each lane loads a float4 slice of its group's
// embedding row -> one wave-instruction issues 4 independent 256 B gathers.
// Cross-group shfl_xor(16,32) reduce; group 0 stores the row (float4).
// Degree-0 rows write 0 (covers the 0xAA-poisoned output, no zero pass).
// ---------------------------------------------------------------------------
__global__ __launch_bounds__(256) void spmm_kernel(
        const int* __restrict__ rowptr, const int2* __restrict__ pairS,
        const float* __restrict__ emb,
        float* __restrict__ outp, int nrows, int row_off) {
    int gw = (int)(((long long)blockIdx.x * blockDim.x + threadIdx.x) >> 6);
    int lane = threadIdx.x & 63;
    if (gw >= nrows) return;
    int g = lane >> 4;          // edge group 0..3
    int q = lane & 15;          // float4 slice within row
    int s = rowptr[row_off + gw];
    int e = rowptr[row_off + gw + 1];
    float ax = 0.0f, ay = 0.0f, az = 0.0f, aw = 0.0f;
    for (int k = s + g; k < e; k += 4) {
        int2 p = pairS[k];                       // broadcast within group
        float v = __int_as_float(p.y);
        const float4* row = (const float4*)(emb + (size_t)p.x * DIM);
        float4 x = row[q];
        ax += v * x.x; ay += v * x.y; az += v * x.z; aw += v * x.w;
    }
    // reduce the 4 edge-groups (lanes l, l^16, l^32, l^48 share slice q)
    ax += __shfl_xor(ax, 16, 64); ay += __shfl_xor(ay, 16, 64);
    az += __shfl_xor(az, 16, 64); aw += __shfl_xor(aw, 16, 64);
    ax += __shfl_xor(ax, 32, 64); ay += __shfl_xor(ay, 32, 64);
    az += __shfl_xor(az, 32, 64); aw += __shfl_xor(aw, 32, 64);
    if (g == 0) {
        float4* orow = (float4*)(outp + (size_t)gw * DIM);
        orow[q] = make_float4(ax, ay, az, aw);
    }
}

// ---------------------------------------------------------------------------
// Fallback (R8 path): direct fp-atomic accumulate — used only if ws too small.
// ---------------------------------------------------------------------------
__global__ __launch_bounds__(256) void edge_atomic_kernel(
        const int* __restrict__ a, const int* __restrict__ b,
        const int* __restrict__ flag,
        const float* __restrict__ ev,
        const float* __restrict__ uemb, const float* __restrict__ iemb,
        float* __restrict__ outU, float* __restrict__ outI) {
    int sw = flag[3];
    const int* eu = sw ? b : a;
    const int* ei = sw ? a : b;
    long long t = (long long)blockIdx.x * blockDim.x + threadIdx.x;
    int lane = (int)(t & 63);
    long long e = t >> 6;
    if (e >= NE) return;
    int u = iclamp(eu[e], 0, NU - 1);
    int i = iclamp(ei[e], 0, NI - 1);
    float v  = ev[e];
    float xu = uemb[(size_t)u * DIM + lane];
    float xi = iemb[(size_t)i * DIM + lane];
    atomicAdd(&outU[(size_t)u * DIM + lane], v * xi);
    atomicAdd(&outI[(size_t)i * DIM + lane], v * xu);
}

// ===========================================================================
extern "C" void kernel_launch(void* const* d_in, const int* in_sizes, int n_in,
                              void* d_out, int out_size, void* d_ws, size_t ws_size,
                              hipStream_t stream) {
    // Identify embedding slots by element count (insurance against slot swap).
    const float* user_emb = (const float*)d_in[0];
    const float* item_emb = (const float*)d_in[1];
    if (in_sizes[0] == NI * DIM && in_sizes[1] == NU * DIM) {
        user_emb = (const float*)d_in[1];
        item_emb = (const float*)d_in[0];
    }
    const int*   edge_a   = (const int*)d_in[2];
    const int*   edge_b   = (const int*)d_in[3];
    const float* edge_val = (const float*)d_in[4];

    float* out = (float*)d_out;                 // F32 output
    float* out_users = out;                     // users first
    float* out_items = out + (size_t)NU * DIM;

    const long long NOUT = (long long)(NU + NI) * DIM;   // 19.2M f32

    // Workspace layout (4 B units; rowptr padded to NT+2 so pairS is 8 B aligned):
    //  flag[16] | cnt[NT] | rowptr[NT+2] | cursor[NT] | bsum[256] | pairS[2*NE int2]
    int* flag = (int*)d_ws;
    const size_t head_units = (size_t)16 + NT + (NT + 2) + NT + 256;   // even
    const size_t need_units = head_units + (size_t)4 * NE;             // + 2*NE int2
    const size_t need_bytes = need_units * 4;

    if (ws_size >= need_bytes) {
        int*  cnt    = flag + 16;
        int*  rowptr = cnt + NT;
        int*  cursor = rowptr + NT + 2;
        int*  bsum   = cursor + NT;
        int2* pairS  = (int2*)(bsum + 256);

        // flag + cnt must start at zero every launch.
        zero_i32_kernel<<<1024, 256, 0, stream>>>(flag, 16 + (long long)NT);
        edge_detect_kernel<<<512, 256, 0, stream>>>(edge_a, edge_b, NE, flag);
        finalize_kernel<<<1, 64, 0, stream>>>(flag);
        hist_kernel<<<1600, 256, 0, stream>>>(edge_a, edge_b, flag, cnt);
        scan1_kernel<<<NB, 256, 0, stream>>>(cnt, bsum);
        scan2_kernel<<<1, 256, 0, stream>>>(bsum);
        scan3_kernel<<<NB, 256, 0, stream>>>(cnt, bsum, rowptr, cursor);
        scatter_kernel<<<3200, 256, 0, stream>>>(edge_a, edge_b, flag, edge_val,
                                                 cursor, pairS);
        // users: gather item rows; items: gather user rows.
        spmm_kernel<<<(NU * 64 + 255) / 256, 256, 0, stream>>>(
            rowptr, pairS, item_emb, out_users, NU, 0);
        spmm_kernel<<<(NI * 64 + 255) / 256, 256, 0, stream>>>(
            rowptr, pairS, user_emb, out_items, NI, NU);
    } else {
        // Fallback: proven R8 atomic path.
        zero_i32_kernel<<<1, 64, 0, stream>>>(flag, 16);
        edge_detect_kernel<<<512, 256, 0, stream>>>(edge_a, edge_b, NE, flag);
        finalize_kernel<<<1, 64, 0, stream>>>(flag);
        zero_f32_kernel<<<2048, 256, 0, stream>>>(out, NOUT);
        long long nthreads = (long long)NE * 64;
        edge_atomic_kernel<<<(int)(nthreads / 256), 256, 0, stream>>>(
            edge_a, edge_b, flag, edge_val, user_emb, item_emb, out_users, out_items);
    }
}

// Round 6
// 1012.671 us; speedup vs baseline: 1.2442x; 1.2442x over previous
//
#include <hip/hip_runtime.h>

// Problem constants (from reference)
#define NU 200000
#define NI 100000
#define DIM 64
#define NE 3200000
#define NT (NU + NI)                     // concatenated destination count
#define CHUNK 2048                       // elements per scan block (256 thr x 8)
#define NB ((NT + CHUNK - 1) / CHUNK)    // 147 scan blocks

static_assert(NB <= 256, "scan2 assumes block sums fit one 256-thread block");
static_assert((NE & 3) == 0, "int4 edge vectorization assumes NE % 4 == 0");

// Established (R0-R8):
//  - ALL float inputs f32; edges int32, dict order. Output F32, users then items.
//  - Edge-order detector (flag[3]) validated in R7.
// Scatter A/B history (the phase is ~1/2 the runtime):
//  R11: two 4 B dword stores/slot to colS+valS (far apart), cursor atomics,
//       3200 blocks -> 360 us @ 595 MB WRITE (1.7 TB/s). PROVEN FASTEST.
//  R12: one 8 B dwordx2 packed store/slot, 1600 blocks -> 575 us @ 396 MB.
//  R13: same packed store, 3200 blocks, 80% occ -> 590 us @ 396 MB.
//  => scattered dwordx2 is ~2-3x slower per-store than scattered dword on
//  gfx950 regardless of parallelism; byte/sector count is NOT the limiter.
// R14: scatter reverted to exact R11 form. spmm deepened: 2x unrolled k-loop
//  (slots k, k+4 per 16-lane group) + dual float4 accumulators = 8 concurrent
//  256 B row-gathers per wave (was 4) to attack gather latency.

__device__ __forceinline__ int iclamp(int x, int lo, int hi) {
    return x < lo ? lo : (x > hi ? hi : x);
}

__global__ void zero_i32_kernel(int* __restrict__ p, long long n) {
    long long i = (long long)blockIdx.x * blockDim.x + threadIdx.x;
    long long stride = (long long)gridDim.x * blockDim.x;
    for (; i < n; i += stride) p[i] = 0;
}

__global__ void zero_f32_kernel(float* __restrict__ p, long long n) {
    long long i = (long long)blockIdx.x * blockDim.x + threadIdx.x;
    long long stride = (long long)gridDim.x * blockDim.x;
    for (; i < n; i += stride) p[i] = 0.0f;
}

// flag: [3]=edge_swap  [10]=maxA [11]=maxB  (validated in R7)
__global__ void edge_detect_kernel(const int* __restrict__ a, const int* __restrict__ b,
                                   int n, int* __restrict__ flag) {
    int i = blockIdx.x * blockDim.x + threadIdx.x;
    int stride = gridDim.x * blockDim.x;
    int ma = 0, mb = 0;
    for (; i < n; i += stride) {
        ma = max(ma, a[i]);
        mb = max(mb, b[i]);
    }
    #pragma unroll
    for (int d = 32; d > 0; d >>= 1) {
        ma = max(ma, __shfl_down(ma, d, 64));
        mb = max(mb, __shfl_down(mb, d, 64));
    }
    if ((threadIdx.x & 63) == 0) {
        atomicMax(&flag[10], ma);
        atomicMax(&flag[11], mb);
    }
}
__global__ void finalize_kernel(int* __restrict__ flag) {
    if (threadIdx.x == 0 && blockIdx.x == 0) {
        int ma = flag[10], mb = flag[11];
        flag[3] = (mb >= NI && ma < NI) ? 1 : 0;
    }
}

// ---------------------------------------------------------------------------
// CSR build: histogram over concatenated destinations (users [0,NU), items
// [NU,NT)). int4-vectorized edge reads; int atomics are cheap packets.
// ---------------------------------------------------------------------------
__global__ __launch_bounds__(256) void hist_kernel(
        const int* __restrict__ a, const int* __restrict__ b,
        const int* __restrict__ flag, int* __restrict__ cnt) {
    int sw = flag[3];
    const int4* eu4 = (const int4*)(sw ? b : a);
    const int4* ei4 = (const int4*)(sw ? a : b);
    int e4 = blockIdx.x * blockDim.x + threadIdx.x;
    int stride = gridDim.x * blockDim.x;
    for (; e4 < NE / 4; e4 += stride) {
        int4 uu = eu4[e4];
        int4 ii = ei4[e4];
        atomicAdd(&cnt[iclamp(uu.x, 0, NU - 1)], 1);
        atomicAdd(&cnt[iclamp(uu.y, 0, NU - 1)], 1);
        atomicAdd(&cnt[iclamp(uu.z, 0, NU - 1)], 1);
        atomicAdd(&cnt[iclamp(uu.w, 0, NU - 1)], 1);
        atomicAdd(&cnt[NU + iclamp(ii.x, 0, NI - 1)], 1);
        atomicAdd(&cnt[NU + iclamp(ii.y, 0, NI - 1)], 1);
        atomicAdd(&cnt[NU + iclamp(ii.z, 0, NI - 1)], 1);
        atomicAdd(&cnt[NU + iclamp(ii.w, 0, NI - 1)], 1);
    }
}

// Two-level exclusive scan over cnt[0..NT). User region sums to exactly NE,
// so rowptr[u] in [0,NE) and rowptr[NU+i] in [NE,2NE): one combined slot space.
__global__ __launch_bounds__(256) void scan1_kernel(const int* __restrict__ cnt,
                                                    int* __restrict__ bsum) {
    int b = blockIdx.x, t = threadIdx.x;
    int base = b * CHUNK;
    int sum = 0;
    #pragma unroll
    for (int k = 0; k < 8; ++k) {
        int idx = base + k * 256 + t;
        if (idx < NT) sum += cnt[idx];
    }
    #pragma unroll
    for (int d = 32; d > 0; d >>= 1) sum += __shfl_down(sum, d, 64);
    __shared__ int wsum[4];
    if ((t & 63) == 0) wsum[t >> 6] = sum;
    __syncthreads();
    if (t == 0) bsum[b] = wsum[0] + wsum[1] + wsum[2] + wsum[3];
}

__global__ __launch_bounds__(256) void scan2_kernel(int* __restrict__ bsum) {
    __shared__ int sh[256];
    int t = threadIdx.x;
    sh[t] = (t < NB) ? bsum[t] : 0;
    __syncthreads();
    for (int off = 1; off < 256; off <<= 1) {
        int v = (t >= off) ? sh[t - off] : 0;
        __syncthreads();
        sh[t] += v;
        __syncthreads();
    }
    if (t < NB) bsum[t] = (t == 0) ? 0 : sh[t - 1];   // exclusive
}

__global__ __launch_bounds__(256) void scan3_kernel(const int* __restrict__ cnt,
                                                    const int* __restrict__ bsum,
                                                    int* __restrict__ rowptr,
                                                    int* __restrict__ cursor) {
    int b = blockIdx.x, t = threadIdx.x;
    int base = b * CHUNK + t * 8;     // 8 contiguous elements per thread
    int v[8];
    int s = 0;
    #pragma unroll
    for (int k = 0; k < 8; ++k) {
        int idx = base + k;
        v[k] = (idx < NT) ? cnt[idx] : 0;
        s += v[k];
    }
    __shared__ int sh[256];
    sh[t] = s;
    __syncthreads();
    for (int off = 1; off < 256; off <<= 1) {
        int x = (t >= off) ? sh[t - off] : 0;
        __syncthreads();
        sh[t] += x;
        __syncthreads();
    }
    int run = (t == 0 ? 0 : sh[t - 1]) + bsum[b];
    #pragma unroll
    for (int k = 0; k < 8; ++k) {
        int idx = base + k;
        if (idx < NT) {
            rowptr[idx] = run;
            cursor[idx] = run;
            run += v[k];
        }
        if (idx == NT - 1) rowptr[NT] = run;   // == 2*NE
    }
}

// Scatter edges into sorted slots — EXACT R11 form (proven 360 us / 1.7 TB/s):
// two scattered 4 B dword stores per slot into two separate arrays. Scattered
// dwordx2 measured 2-3x slower per-store (R12/R13); do not re-pack.
// Every slot in colS/valS[0..2*NE) is written exactly once; no pre-zero needed.
__global__ __launch_bounds__(256) void scatter_kernel(
        const int* __restrict__ a, const int* __restrict__ b,
        const int* __restrict__ flag, const float* __restrict__ ev,
        int* __restrict__ cursor, int* __restrict__ colS, float* __restrict__ valS) {
    int sw = flag[3];
    const int* eu = sw ? b : a;
    const int* ei = sw ? a : b;
    int e = blockIdx.x * blockDim.x + threadIdx.x;
    int stride = gridDim.x * blockDim.x;
    for (; e < NE; e += stride) {
        int u = iclamp(eu[e], 0, NU - 1);
        int i = iclamp(ei[e], 0, NI - 1);
        float v = ev[e];
        int p0 = atomicAdd(&cursor[u], 1);       // user slot: stores item idx
        colS[p0] = i; valS[p0] = v;
        int p1 = atomicAdd(&cursor[NU + i], 1);  // item slot: stores user idx
        colS[p1] = u; valS[p1] = v;
    }
}

// ---------------------------------------------------------------------------
// Gather SpMM: one wave per output row. 16-lane groups (g = lane>>4) each own
// one edge slot per step; lane loads a float4 slice of the group's embedding
// row. 2x manual unroll (slots k and k+4) with dual accumulators -> 8
// independent 256 B row-gathers in flight per wave (attacks gather latency).
// Cross-group shfl_xor(16,32) reduce; group 0 stores the row (float4).
// Degree-0 rows write 0 (covers the 0xAA-poisoned output, no zero pass).
// ---------------------------------------------------------------------------
__global__ __launch_bounds__(256) void spmm_kernel(
        const int* __restrict__ rowptr, const int* __restrict__ colS,
        const float* __restrict__ valS, const float* __restrict__ emb,
        float* __restrict__ outp, int nrows, int row_off) {
    int gw = (int)(((long long)blockIdx.x * blockDim.x + threadIdx.x) >> 6);
    int lane = threadIdx.x & 63;
    if (gw >= nrows) return;
    int g = lane >> 4;          // edge group 0..3
    int q = lane & 15;          // float4 slice within row
    int s = rowptr[row_off + gw];
    int e = rowptr[row_off + gw + 1];
    float ax0 = 0.f, ay0 = 0.f, az0 = 0.f, aw0 = 0.f;
    float ax1 = 0.f, ay1 = 0.f, az1 = 0.f, aw1 = 0.f;
    int k = s + g;
    for (; k + 4 < e; k += 8) {              // both k and k+4 valid
        int c0 = colS[k];     float v0 = valS[k];
        int c1 = colS[k + 4]; float v1 = valS[k + 4];
        float4 x0 = ((const float4*)(emb + (size_t)c0 * DIM))[q];
        float4 x1 = ((const float4*)(emb + (size_t)c1 * DIM))[q];
        ax0 += v0 * x0.x; ay0 += v0 * x0.y; az0 += v0 * x0.z; aw0 += v0 * x0.w;
        ax1 += v1 * x1.x; ay1 += v1 * x1.y; az1 += v1 * x1.z; aw1 += v1 * x1.w;
    }
    if (k < e) {                             // at most one leftover per group
        int c = colS[k]; float v = valS[k];
        float4 x = ((const float4*)(emb + (size_t)c * DIM))[q];
        ax0 += v * x.x; ay0 += v * x.y; az0 += v * x.z; aw0 += v * x.w;
    }
    float ax = ax0 + ax1, ay = ay0 + ay1, az = az0 + az1, aw = aw0 + aw1;
    // reduce the 4 edge-groups (lanes l, l^16, l^32, l^48 share slice q)
    ax += __shfl_xor(ax, 16, 64); ay += __shfl_xor(ay, 16, 64);
    az += __shfl_xor(az, 16, 64); aw += __shfl_xor(aw, 16, 64);
    ax += __shfl_xor(ax, 32, 64); ay += __shfl_xor(ay, 32, 64);
    az += __shfl_xor(az, 32, 64); aw += __shfl_xor(aw, 32, 64);
    if (g == 0) {
        float4* orow = (float4*)(outp + (size_t)gw * DIM);
        orow[q] = make_float4(ax, ay, az, aw);
    }
}

// ---------------------------------------------------------------------------
// Fallback (R8 path): direct fp-atomic accumulate — used only if ws too small.
// ---------------------------------------------------------------------------
__global__ __launch_bounds__(256) void edge_atomic_kernel(
        const int* __restrict__ a, const int* __restrict__ b,
        const int* __restrict__ flag,
        const float* __restrict__ ev,
        const float* __restrict__ uemb, const float* __restrict__ iemb,
        float* __restrict__ outU, float* __restrict__ outI) {
    int sw = flag[3];
    const int* eu = sw ? b : a;
    const int* ei = sw ? a : b;
    long long t = (long long)blockIdx.x * blockDim.x + threadIdx.x;
    int lane = (int)(t & 63);
    long long e = t >> 6;
    if (e >= NE) return;
    int u = iclamp(eu[e], 0, NU - 1);
    int i = iclamp(ei[e], 0, NI - 1);
    float v  = ev[e];
    float xu = uemb[(size_t)u * DIM + lane];
    float xi = iemb[(size_t)i * DIM + lane];
    atomicAdd(&outU[(size_t)u * DIM + lane], v * xi);
    atomicAdd(&outI[(size_t)i * DIM + lane], v * xu);
}

// ===========================================================================
extern "C" void kernel_launch(void* const* d_in, const int* in_sizes, int n_in,
                              void* d_out, int out_size, void* d_ws, size_t ws_size,
                              hipStream_t stream) {
    // Identify embedding slots by element count (insurance against slot swap).
    const float* user_emb = (const float*)d_in[0];
    const float* item_emb = (const float*)d_in[1];
    if (in_sizes[0] == NI * DIM && in_sizes[1] == NU * DIM) {
        user_emb = (const float*)d_in[1];
        item_emb = (const float*)d_in[0];
    }
    const int*   edge_a   = (const int*)d_in[2];
    const int*   edge_b   = (const int*)d_in[3];
    const float* edge_val = (const float*)d_in[4];

    float* out = (float*)d_out;                 // F32 output
    float* out_users = out;                     // users first
    float* out_items = out + (size_t)NU * DIM;

    const long long NOUT = (long long)(NU + NI) * DIM;   // 19.2M f32

    // Workspace layout (4 B units) — R11 layout:
    //  flag[16] | cnt[NT] | rowptr[NT+1] | cursor[NT] | bsum[256] |
    //  colS[2*NE] | valS[2*NE]
    int* flag = (int*)d_ws;
    const size_t need_units = (size_t)16 + NT + (NT + 1) + NT + 256
                            + (size_t)2 * NE + (size_t)2 * NE;
    const size_t need_bytes = need_units * 4;

    if (ws_size >= need_bytes) {
        int*   cnt    = flag + 16;
        int*   rowptr = cnt + NT;
        int*   cursor = rowptr + NT + 1;
        int*   bsum   = cursor + NT;
        int*   colS   = bsum + 256;
        float* valS   = (float*)(colS + (size_t)2 * NE);

        // flag + cnt must start at zero every launch.
        zero_i32_kernel<<<1024, 256, 0, stream>>>(flag, 16 + (long long)NT);
        edge_detect_kernel<<<512, 256, 0, stream>>>(edge_a, edge_b, NE, flag);
        finalize_kernel<<<1, 64, 0, stream>>>(flag);
        hist_kernel<<<1600, 256, 0, stream>>>(edge_a, edge_b, flag, cnt);
        scan1_kernel<<<NB, 256, 0, stream>>>(cnt, bsum);
        scan2_kernel<<<1, 256, 0, stream>>>(bsum);
        scan3_kernel<<<NB, 256, 0, stream>>>(cnt, bsum, rowptr, cursor);
        scatter_kernel<<<3200, 256, 0, stream>>>(edge_a, edge_b, flag, edge_val,
                                                 cursor, colS, valS);
        // users: gather item rows; items: gather user rows.
        spmm_kernel<<<(NU * 64 + 255) / 256, 256, 0, stream>>>(
            rowptr, colS, valS, item_emb, out_users, NU, 0);
        spmm_kernel<<<(NI * 64 + 255) / 256, 256, 0, stream>>>(
            rowptr, colS, valS, user_emb, out_items, NI, NU);
    } else {
        // Fallback: proven R8 atomic path.
        zero_i32_kernel<<<1, 64, 0, stream>>>(flag, 16);
        edge_detect_kernel<<<512, 256, 0, stream>>>(edge_a, edge_b, NE, flag);
        finalize_kernel<<<1, 64, 0, stream>>>(flag);
        zero_f32_kernel<<<2048, 256, 0, stream>>>(out, NOUT);
        long long nthreads = (long long)NE * 64;
        edge_atomic_kernel<<<(int)(nthreads / 256), 256, 0, stream>>>(
            edge_a, edge_b, flag, edge_val, user_emb, item_emb, out_users, out_items);
    }
}